// Round 1
// baseline (547.842 us; speedup 1.0000x reference)
//
#include <hip/hip_runtime.h>
#include <hip/hip_bf16.h>

// Problem: channel_attention. Key identity: einsum('bocs,bocm->bocs', x, softmax(score))
// multiplies x by the softmax row-sum == 1, so q/k/atten are dead code (affects output
// only at ~1e-7, threshold is 1e-1). Reduces to: out[g,c,s] = LN_c(Wp @ x[g,:,s] + bp).
//
// g = b*o in [0,128), C=128 channels, S=3000 columns.
// Per group: Y = Wp[128x128] @ X[128x3000], then per-column LayerNorm over the 128
// channels, same [c][s] layout in and out (no transposes materialized).

#define C   128
#define SEQ 3000
#define TS  64     // columns per block
#define NG  128    // 32*4 groups

// Transpose Wp [c][m] -> WpT [m][c] so the GEMM loop can vector-load 8 consecutive
// output-channel weights per k-step. 64KB, lives in d_ws, rewritten every launch.
__global__ void transpose_wp(const float* __restrict__ Wp, float* __restrict__ WpT) {
    int t = blockIdx.x * blockDim.x + threadIdx.x;
    if (t < C * C) {
        int m = t >> 7;
        int c = t & (C - 1);
        WpT[m * C + c] = Wp[c * C + m];
    }
}

__global__ __launch_bounds__(256) void fused_gemm_ln(
    const float* __restrict__ x,    // [NG][C][SEQ]
    const float* __restrict__ WpT,  // [C(m)][C(c)]
    const float* __restrict__ bp,   // [C]
    const float* __restrict__ gp,   // [C]
    const float* __restrict__ bep,  // [C]
    float* __restrict__ out)        // [NG][C][SEQ]
{
    __shared__ __align__(16) float Xs[C][TS];     // 32 KB X tile
    __shared__ float psum[16][TS];                // 4 KB LN partial sums
    __shared__ float psq[16][TS];                 // 4 KB LN partial sumsq
    __shared__ float mean_s[TS];
    __shared__ float rstd_s[TS];

    const int g  = blockIdx.y;
    const int s0 = blockIdx.x * TS;
    const float* xg = x + (size_t)g * (C * SEQ);
    float* og = out + (size_t)g * (C * SEQ);
    const int t = threadIdx.x;

    // ---- stage X tile: 128 rows x 64 cols, float4 per thread x 8 iters, coalesced.
    // SEQ % 4 == 0 and tiles are 64-aligned, so float4 groups are wholly valid/invalid.
    #pragma unroll
    for (int i = 0; i < 8; ++i) {
        int q  = t + i * 256;          // quad index 0..2047
        int m  = q >> 4;               // row 0..127
        int sl = (q & 15) << 2;        // col 0,4,..,60
        int sg = s0 + sl;
        float4 v = make_float4(0.f, 0.f, 0.f, 0.f);
        if (sg < SEQ) v = *(const float4*)(xg + (size_t)m * SEQ + sg);
        *(float4*)&Xs[m][sl] = v;
    }
    __syncthreads();

    // ---- register-tile GEMM: thread owns 8 channels x 4 columns
    const int squad = t & 15;          // column quad
    const int coct  = t >> 4;          // channel octet
    const int c0  = coct << 3;
    const int sl0 = squad << 2;

    float acc[8][4];
    #pragma unroll
    for (int i = 0; i < 8; ++i)
        #pragma unroll
        for (int j = 0; j < 4; ++j) acc[i][j] = 0.f;

    #pragma unroll 2
    for (int m = 0; m < C; ++m) {
        const float4 xv = *(const float4*)&Xs[m][sl0];
        const float4 w0 = *(const float4*)(WpT + m * C + c0);
        const float4 w1 = *(const float4*)(WpT + m * C + c0 + 4);
        float xr[4] = {xv.x, xv.y, xv.z, xv.w};
        float wr[8] = {w0.x, w0.y, w0.z, w0.w, w1.x, w1.y, w1.z, w1.w};
        #pragma unroll
        for (int i = 0; i < 8; ++i)
            #pragma unroll
            for (int j = 0; j < 4; ++j)
                acc[i][j] = fmaf(wr[i], xr[j], acc[i][j]);
    }

    // ---- add bias, per-thread LN partials over the 8 owned channels
    float bb[8];
    {
        float4 b0 = *(const float4*)(bp + c0);
        float4 b1 = *(const float4*)(bp + c0 + 4);
        bb[0]=b0.x; bb[1]=b0.y; bb[2]=b0.z; bb[3]=b0.w;
        bb[4]=b1.x; bb[5]=b1.y; bb[6]=b1.z; bb[7]=b1.w;
    }
    float ps[4] = {0.f,0.f,0.f,0.f};
    float pq[4] = {0.f,0.f,0.f,0.f};
    #pragma unroll
    for (int i = 0; i < 8; ++i) {
        #pragma unroll
        for (int j = 0; j < 4; ++j) {
            float y = acc[i][j] + bb[i];
            acc[i][j] = y;
            ps[j] += y;
            pq[j] += y * y;
        }
    }
    #pragma unroll
    for (int j = 0; j < 4; ++j) {
        psum[coct][sl0 + j] = ps[j];
        psq [coct][sl0 + j] = pq[j];
    }
    __syncthreads();

    // ---- per-column mean/rstd (64 columns, 1 thread each)
    if (t < TS) {
        float s = 0.f, q = 0.f;
        #pragma unroll
        for (int j = 0; j < 16; ++j) { s += psum[j][t]; q += psq[j][t]; }
        float mean = s * (1.0f / C);
        float var  = q * (1.0f / C) - mean * mean;
        mean_s[t] = mean;
        rstd_s[t] = rsqrtf(var + 1e-5f);
    }
    __syncthreads();

    // ---- normalize + gamma/beta + store (float4 per channel row, coalesced)
    float gg[8], ee[8];
    {
        float4 g0 = *(const float4*)(gp + c0);
        float4 g1 = *(const float4*)(gp + c0 + 4);
        float4 e0 = *(const float4*)(bep + c0);
        float4 e1 = *(const float4*)(bep + c0 + 4);
        gg[0]=g0.x; gg[1]=g0.y; gg[2]=g0.z; gg[3]=g0.w;
        gg[4]=g1.x; gg[5]=g1.y; gg[6]=g1.z; gg[7]=g1.w;
        ee[0]=e0.x; ee[1]=e0.y; ee[2]=e0.z; ee[3]=e0.w;
        ee[4]=e1.x; ee[5]=e1.y; ee[6]=e1.z; ee[7]=e1.w;
    }
    float mn[4], rs[4];
    #pragma unroll
    for (int j = 0; j < 4; ++j) { mn[j] = mean_s[sl0 + j]; rs[j] = rstd_s[sl0 + j]; }

    if (s0 + sl0 < SEQ) {
        #pragma unroll
        for (int i = 0; i < 8; ++i) {
            float4 o;
            o.x = (acc[i][0] - mn[0]) * rs[0] * gg[i] + ee[i];
            o.y = (acc[i][1] - mn[1]) * rs[1] * gg[i] + ee[i];
            o.z = (acc[i][2] - mn[2]) * rs[2] * gg[i] + ee[i];
            o.w = (acc[i][3] - mn[3]) * rs[3] * gg[i] + ee[i];
            *(float4*)(og + (size_t)(c0 + i) * SEQ + s0 + sl0) = o;
        }
    }
}

extern "C" void kernel_launch(void* const* d_in, const int* in_sizes, int n_in,
                              void* d_out, int out_size, void* d_ws, size_t ws_size,
                              hipStream_t stream) {
    // setup_inputs order: x, Wq, bq, gq, betaq, Wk, bk, gk, betak, Wp, bp, gp, betap
    const float* x   = (const float*)d_in[0];
    const float* Wp  = (const float*)d_in[9];
    const float* bp  = (const float*)d_in[10];
    const float* gp  = (const float*)d_in[11];
    const float* bep = (const float*)d_in[12];
    float* out = (float*)d_out;
    float* WpT = (float*)d_ws;   // 64 KB scratch

    hipLaunchKernelGGL(transpose_wp, dim3(64), dim3(256), 0, stream, Wp, WpT);

    dim3 grid((SEQ + TS - 1) / TS, NG);
    hipLaunchKernelGGL(fused_gemm_ln, grid, dim3(256), 0, stream,
                       x, WpT, bp, gp, bep, out);
}

// Round 2
// 398.430 us; speedup vs baseline: 1.3750x; 1.3750x over previous
//
#include <hip/hip_runtime.h>
#include <hip/hip_bf16.h>

// channel_attention: einsum('bocs,bocm->bocs', x, softmax(score)) contracts m which
// only appears in score => multiplies x by softmax row-sum == 1 (within fp32 eps).
// So q/k/atten are dead code and the problem is exactly:
//   out[g,c,s] = LN_c( sum_m Wp[c][m] * x[g][m][s] + bp[c] ) * gp[c] + betap[c]
// g = b*o in [0,128). Per group: GEMM M=C=128, N=3000, K=128, + per-column LN.
//
// bf16 MFMA version. W is A-operand ([c][m], k contiguous natively). X must be
// transposed to [s][m] bf16 in LDS; XOR chunk swizzle keeps both the transpose
// ds_write_b128 pattern and the fragment ds_read_b128 pattern <=2-way (free).

#define C    128
#define SEQ  3000
#define NG   128
#define NT   128                       // columns per block
#define NBLK ((SEQ + NT - 1) / NT)     // 24

typedef float f4 __attribute__((ext_vector_type(4)));
typedef short short8 __attribute__((ext_vector_type(8)));

__device__ __forceinline__ unsigned short f2bf(float f) {
    union { float f; unsigned u; } v; v.f = f;
    unsigned r = v.u + 0x7fffu + ((v.u >> 16) & 1u);   // RNE
    return (unsigned short)(r >> 16);
}

// 16B-chunk XOR swizzle: injective over 16 consecutive rows (frag reads) and over
// the transpose-write lane pattern (sl = 4*l'+j vs l'), both verified <=2-way.
__device__ __forceinline__ int swz(int row, int chunk) {
    return chunk ^ ((row ^ (row >> 2)) & 15);
}

__global__ void cvt_wp(const float* __restrict__ Wp, unsigned short* __restrict__ out) {
    int i = blockIdx.x * 256 + threadIdx.x;
    if (i < C * C) out[i] = f2bf(Wp[i]);
}

__global__ __launch_bounds__(256, 2) void gemm_ln_mfma(
    const float* __restrict__ x,             // [NG][C][SEQ] fp32
    const unsigned short* __restrict__ wbf,  // [C][C] bf16 (c-major, m contiguous)
    const float* __restrict__ bp,
    const float* __restrict__ gp,
    const float* __restrict__ bep,
    float* __restrict__ out)                 // [NG][C][SEQ] fp32
{
    __shared__ __align__(16) unsigned short Wl[C * C];   // 32 KB, [c][m] swizzled
    __shared__ __align__(16) unsigned short Xl[NT * C];  // 32 KB, [s][m] swizzled

    const int g  = blockIdx.y;
    const int s0 = blockIdx.x * NT;
    const float* xg = x + (size_t)g * (C * SEQ);
    float* og = out + (size_t)g * (C * SEQ);
    const int t = threadIdx.x;

    // ---- stage W: 2048 16B chunks, one uint4 global load + one ds_write_b128 each
    {
        const uint4* wsrc = (const uint4*)wbf;
        #pragma unroll
        for (int i = 0; i < 8; ++i) {
            int cid = t + 256 * i;           // 0..2047
            int c  = cid >> 4;
            int ch = cid & 15;
            uint4 v = wsrc[cid];
            *(uint4*)&Wl[c * C + swz(c, ch) * 8] = v;
        }
    }

    // ---- stage X transposed: thread owns (m-chunk, s-quad); 8x4 in-register
    // transpose; writes 4 x 16B rows of 8 bf16 (m contiguous).
    {
        const int sq  = t & 31;              // s-quad 0..31 (consecutive lanes -> coalesced)
        const int mcb = t >> 5;              // 0..7
        const int s_loc  = 4 * sq;
        const int s_glob = s0 + s_loc;
        const bool valid = (s_glob + 3) < SEQ;
        #pragma unroll
        for (int half = 0; half < 2; ++half) {
            const int mc = mcb + 8 * half;   // m-chunk 0..15
            f4 r[8];
            const float* xp = xg + (size_t)(mc * 8) * SEQ + s_glob;
            #pragma unroll
            for (int rr = 0; rr < 8; ++rr) {
                if (valid) r[rr] = *(const f4*)(xp + (size_t)rr * SEQ);
                else       r[rr] = (f4){0.f, 0.f, 0.f, 0.f};
            }
            #pragma unroll
            for (int j = 0; j < 4; ++j) {
                const int sl = s_loc + j;
                uint4 pk;
                pk.x = (unsigned)f2bf(r[0][j]) | ((unsigned)f2bf(r[1][j]) << 16);
                pk.y = (unsigned)f2bf(r[2][j]) | ((unsigned)f2bf(r[3][j]) << 16);
                pk.z = (unsigned)f2bf(r[4][j]) | ((unsigned)f2bf(r[5][j]) << 16);
                pk.w = (unsigned)f2bf(r[6][j]) | ((unsigned)f2bf(r[7][j]) << 16);
                *(uint4*)&Xl[sl * C + swz(sl, mc) * 8] = pk;
            }
        }
    }
    __syncthreads();

    // ---- MFMA: wave owns 32-col strip x all 128 channels (LN fully in-wave)
    const int w    = t >> 6;
    const int lane = t & 63;
    const int col  = lane & 15;
    const int quad = lane >> 4;

    f4 acc[2][8];   // [nt][mt], 64 VGPRs
    #pragma unroll
    for (int nt = 0; nt < 2; ++nt)
        #pragma unroll
        for (int mt = 0; mt < 8; ++mt) acc[nt][mt] = (f4){0.f, 0.f, 0.f, 0.f};

    #pragma unroll
    for (int kc = 0; kc < 4; ++kc) {
        short8 a[8], b[2];
        #pragma unroll
        for (int mt = 0; mt < 8; ++mt) {
            const int row = 16 * mt + col;
            a[mt] = *(const short8*)&Wl[row * C + swz(row, 4 * kc + quad) * 8];
        }
        #pragma unroll
        for (int nt = 0; nt < 2; ++nt) {
            const int srow = 32 * w + 16 * nt + col;
            b[nt] = *(const short8*)&Xl[srow * C + swz(srow, 4 * kc + quad) * 8];
        }
        #pragma unroll
        for (int nt = 0; nt < 2; ++nt)
            #pragma unroll
            for (int mt = 0; mt < 8; ++mt)
                acc[nt][mt] = __builtin_amdgcn_mfma_f32_16x16x32_bf16(
                    a[mt], b[nt], acc[nt][mt], 0, 0, 0);
    }

    // ---- bias + in-wave per-column LayerNorm (rows of a column span the 4 quads)
    #pragma unroll
    for (int mt = 0; mt < 8; ++mt) {
        const f4 b4 = *(const f4*)(bp + 16 * mt + 4 * quad);
        #pragma unroll
        for (int nt = 0; nt < 2; ++nt)
            #pragma unroll
            for (int r = 0; r < 4; ++r) acc[nt][mt][r] += b4[r];
    }

    float mean[2], rstd[2];
    #pragma unroll
    for (int nt = 0; nt < 2; ++nt) {
        float s = 0.f, q = 0.f;
        #pragma unroll
        for (int mt = 0; mt < 8; ++mt)
            #pragma unroll
            for (int r = 0; r < 4; ++r) {
                float y = acc[nt][mt][r];
                s += y; q += y * y;
            }
        s += __shfl_xor(s, 16); q += __shfl_xor(q, 16);
        s += __shfl_xor(s, 32); q += __shfl_xor(q, 32);
        float m = s * (1.0f / C);
        float v = q * (1.0f / C) - m * m;
        mean[nt] = m;
        rstd[nt] = rsqrtf(v + 1e-5f);
    }

    // ---- scale/shift + store
    #pragma unroll
    for (int mt = 0; mt < 8; ++mt) {
        const f4 g4 = *(const f4*)(gp  + 16 * mt + 4 * quad);
        const f4 e4 = *(const f4*)(bep + 16 * mt + 4 * quad);
        #pragma unroll
        for (int nt = 0; nt < 2; ++nt) {
            const int sg = s0 + 32 * w + 16 * nt + col;
            if (sg < SEQ) {
                #pragma unroll
                for (int r = 0; r < 4; ++r) {
                    const int c = 16 * mt + 4 * quad + r;
                    og[(size_t)c * SEQ + sg] =
                        (acc[nt][mt][r] - mean[nt]) * rstd[nt] * g4[r] + e4[r];
                }
            }
        }
    }
}

extern "C" void kernel_launch(void* const* d_in, const int* in_sizes, int n_in,
                              void* d_out, int out_size, void* d_ws, size_t ws_size,
                              hipStream_t stream) {
    // inputs: x, Wq, bq, gq, betaq, Wk, bk, gk, betak, Wp, bp, gp, betap
    const float* x   = (const float*)d_in[0];
    const float* Wp  = (const float*)d_in[9];
    const float* bp  = (const float*)d_in[10];
    const float* gp  = (const float*)d_in[11];
    const float* bep = (const float*)d_in[12];
    float* out = (float*)d_out;
    unsigned short* wbf = (unsigned short*)d_ws;   // 32 KB bf16 weights

    hipLaunchKernelGGL(cvt_wp, dim3(64), dim3(256), 0, stream, Wp, wbf);

    dim3 grid(NBLK, NG);
    hipLaunchKernelGGL(gemm_ln_mfma, grid, dim3(256), 0, stream,
                       x, wbf, bp, gp, bep, out);
}